// Round 13
// baseline (1130.323 us; speedup 1.0000x reference)
//
#include <hip/hip_runtime.h>
#include <hip/hip_cooperative_groups.h>

namespace cg = cooperative_groups;

#define N_NODES 100000
#define NE      1600000
#define C       128
#define NB      98        // buckets of 1024 destination nodes
#define BCAP    20480     // per-bucket capacity; mean 16384, ~32-sigma margin
#define EPB     2048      // edges per binA virtual block
#define NVB_A   ((NE + EPB - 1) / EPB)        // 782
#define NVB_G   ((N_NODES + 63) / 64)         // 1563 gemm vblocks (64 nodes)
#define NVB_S   ((N_NODES + 15) / 16)         // 6250 gather vblocks (16 nodes)

typedef __attribute__((ext_vector_type(8))) short short8;
typedef __attribute__((ext_vector_type(4))) float float4v;

__device__ __forceinline__ unsigned short bf16rne(float f) {
    unsigned int u = __float_as_uint(f);
    return (unsigned short)((u + 0x7FFFu + ((u >> 16) & 1u)) >> 16);
}
__device__ __forceinline__ float blo(unsigned int u) { return __uint_as_float(u << 16); }
__device__ __forceinline__ float bhi(unsigned int u) { return __uint_as_float(u & 0xFFFF0000u); }

struct Prm {
    const float* x;
    const int*   row;
    const int*   col;
    const float* ea;
    const float* W1; const float* W2; const float* W3;
    const float* b1; const float* b2; const float* b3;
    const float* lw; const float* lb;
    float*       out;
    uint2*       babuf;
    uint2*       sedge;
    uint2*       cursor2;
    float*       dinv;
    int*         gbcur;
    unsigned short* Wt;
    unsigned short* xwb;
    unsigned short* hb;
};

union SMem {
    struct { int hcnt[NB]; int hofs[NB]; int hbase[NB]; int lofs[NB];
             uint2 recs[EPB]; int gdst[EPB]; } a;                 // ~25.6 KB
    struct { int cnt[1024]; float deg[1024]; int ofs[1024]; int tsum[256]; } b; // 13 KB
    unsigned short w[64 * 136];                                   // 17.4 KB
};

// ---------------- phase bodies (device funcs) ------------------------------
__device__ void binA_vb(const Prm& p, SMem& sm, int vb) {
    const int t = threadIdx.x;
    for (int i = t; i < NB; i += 256) { sm.a.hcnt[i] = 0; sm.a.hofs[i] = 0; }
    __syncthreads();
    const int e0 = vb * EPB;
    int cc[8], rr[8]; float ee[8];
#pragma unroll
    for (int i = 0; i < 8; i++) {
        int e = e0 + i * 256 + t;
        if (e < NE) { cc[i] = p.col[e]; rr[i] = p.row[e]; ee[i] = p.ea[e]; }
        else cc[i] = -1;
    }
#pragma unroll
    for (int i = 0; i < 8; i++)
        if (cc[i] >= 0) atomicAdd(&sm.a.hcnt[cc[i] >> 10], 1);
    __syncthreads();
    if (t < NB) {
        int c = sm.a.hcnt[t];
        sm.a.hbase[t] = c ? atomicAdd(&p.gbcur[t], c) : 0;
    }
    if (t == 0) {
        int run = 0;
        for (int b = 0; b < NB; b++) { sm.a.lofs[b] = run; run += sm.a.hcnt[b]; }
    }
    __syncthreads();
#pragma unroll
    for (int i = 0; i < 8; i++) {
        if (cc[i] < 0) continue;
        int b = cc[i] >> 10;
        int lpos = atomicAdd(&sm.a.hofs[b], 1);
        int si = sm.a.lofs[b] + lpos;
        unsigned int meta = ((unsigned int)(cc[i] & 1023) << 17) | (unsigned int)rr[i];
        sm.a.recs[si] = make_uint2(meta, __float_as_uint(ee[i]));
        int gp = sm.a.hbase[b] + lpos;
        sm.a.gdst[si] = (gp < BCAP) ? (b * BCAP + gp) : -1;
    }
    __syncthreads();
    const int valid = sm.a.lofs[NB - 1] + sm.a.hcnt[NB - 1];
    for (int i = t; i < valid; i += 256) {
        int g = sm.a.gdst[i];
        if (g >= 0) p.babuf[g] = sm.a.recs[i];
    }
    __syncthreads();   // protect LDS before next vb reuse
}

__device__ void binB_vb(const Prm& p, SMem& sm, int b) {
    const int t = threadIdx.x;
    const int n0 = b << 10;
    const int nn = min(1024, N_NODES - n0);
    for (int i = t; i < 1024; i += 256) { sm.b.cnt[i] = 0; sm.b.deg[i] = 0.f; }
    __syncthreads();
    const int msize = min(p.gbcur[b], BCAP);
    const uint2* bb = p.babuf + (size_t)b * BCAP;
    for (int i = t; i < msize; i += 256) {
        uint2 m = bb[i];
        int cl = m.x >> 17;
        atomicAdd(&sm.b.cnt[cl], 1);
        atomicAdd(&sm.b.deg[cl], __uint_as_float(m.y));
    }
    __syncthreads();
    for (int i = t; i < nn; i += 256)
        p.dinv[n0 + i] = 1.0f / sqrtf(sm.b.deg[i] + 1.0f);
    const int b4 = t * 4;
    int c0 = sm.b.cnt[b4], c1 = sm.b.cnt[b4 + 1], c2 = sm.b.cnt[b4 + 2], c3 = sm.b.cnt[b4 + 3];
    sm.b.tsum[t] = c0 + c1 + c2 + c3;
    __syncthreads();
    for (int off = 1; off < 256; off <<= 1) {
        int v = (t >= off) ? sm.b.tsum[t - off] : 0;
        __syncthreads();
        sm.b.tsum[t] += v;
        __syncthreads();
    }
    int texcl = t ? sm.b.tsum[t - 1] : 0;
    sm.b.ofs[b4]     = texcl;
    sm.b.ofs[b4 + 1] = texcl + c0;
    sm.b.ofs[b4 + 2] = texcl + c0 + c1;
    sm.b.ofs[b4 + 3] = texcl + c0 + c1 + c2;
    __syncthreads();
    const unsigned int ebase = (unsigned int)b * BCAP;
    for (int i = t; i < nn; i += 256) {
        unsigned int st = ebase + (unsigned int)sm.b.ofs[i];
        p.cursor2[n0 + i] = make_uint2(st, st + (unsigned int)sm.b.cnt[i]);
    }
    __syncthreads();
    for (int i = t; i < msize; i += 256) {
        uint2 m = bb[i];
        int cl = m.x >> 17;
        int pp = atomicAdd(&sm.b.ofs[cl], 1);
        p.sedge[(size_t)b * BCAP + pp] = make_uint2(m.x & 0x1FFFFu, m.y);
    }
    __syncthreads();
}

// gemm vblock: 64 nodes x 128 outcols; X frags in registers across 2 W-halves.
__device__ void gemm_vb(const Prm& p, SMem& sm, int vb, int layer) {
    const int t = threadIdx.x;
    const int wave = t >> 6, lane = t & 63;
    const int m = lane & 15, quad = lane >> 4;
    const int nd = vb * 64 + wave * 16 + m;

    short8 xf[4];
#pragma unroll
    for (int kc = 0; kc < 4; kc++) {
        const int k0 = kc * 32 + quad * 8;
        short8 v = (short8){0, 0, 0, 0, 0, 0, 0, 0};
        if (nd < N_NODES) {
            if (layer == 0) {
                float4 f0 = *(const float4*)(p.x + (size_t)nd * 128 + k0);
                float4 f1 = *(const float4*)(p.x + (size_t)nd * 128 + k0 + 4);
                v[0] = (short)bf16rne(f0.x); v[1] = (short)bf16rne(f0.y);
                v[2] = (short)bf16rne(f0.z); v[3] = (short)bf16rne(f0.w);
                v[4] = (short)bf16rne(f1.x); v[5] = (short)bf16rne(f1.y);
                v[6] = (short)bf16rne(f1.z); v[7] = (short)bf16rne(f1.w);
            } else {
                v = *(const short8*)(p.hb + (size_t)nd * 128 + k0);
            }
        }
        xf[kc] = v;
    }
    float dv = (nd < N_NODES) ? p.dinv[nd] : 0.f;

#pragma unroll
    for (int half = 0; half < 2; half++) {
        __syncthreads();   // previous half's LDS reads done
        const uint4* wsrc = (const uint4*)(p.Wt + layer * 16384 + half * 64 * 128);
        for (int i = t; i < 64 * 16; i += 256) {
            int nr = i >> 4, q = i & 15;
            *(uint4*)&sm.w[nr * 136 + q * 8] = wsrc[i];
        }
        __syncthreads();
        float4v acc[4];
#pragma unroll
        for (int tt = 0; tt < 4; tt++) acc[tt] = (float4v){0.f, 0.f, 0.f, 0.f};
#pragma unroll
        for (int kc = 0; kc < 4; kc++) {
            const int k0 = kc * 32 + quad * 8;
#pragma unroll
            for (int tt = 0; tt < 4; tt++) {
                short8 w = *(const short8*)&sm.w[(tt * 16 + m) * 136 + k0];
                acc[tt] = __builtin_amdgcn_mfma_f32_16x16x32_bf16(w, xf[kc], acc[tt], 0, 0, 0);
            }
        }
        if (nd < N_NODES) {
#pragma unroll
            for (int tt = 0; tt < 4; tt++) {
                uint2 o;
                o.x = (unsigned int)bf16rne(acc[tt][0] * dv) |
                      ((unsigned int)bf16rne(acc[tt][1] * dv) << 16);
                o.y = (unsigned int)bf16rne(acc[tt][2] * dv) |
                      ((unsigned int)bf16rne(acc[tt][3] * dv) << 16);
                *(uint2*)&p.xwb[(size_t)nd * 128 + half * 64 + tt * 16 + quad * 4] = o;
            }
        }
    }
    __syncthreads();
}

__device__ void gather_vb(const Prm& p, int vb, const float* bias, bool last) {
    const int t = threadIdx.x;
    int node = vb * 16 + (t >> 4);
    int lane = t & 15;
    if (node >= N_NODES) return;   // no __syncthreads below: safe
    uint2 cu = p.cursor2[node];
    int e = (int)cu.x, end = (int)cu.y;
    const uint4* tab = (const uint4*)p.xwb;

    uint4 q0 = tab[(size_t)node * 16 + lane];
    float4 aL, aH;
    aL.x = blo(q0.x); aL.y = bhi(q0.x); aL.z = blo(q0.y); aL.w = bhi(q0.y);
    aH.x = blo(q0.z); aH.y = bhi(q0.z); aH.z = blo(q0.w); aH.w = bhi(q0.w);

    for (; e + 4 <= end; e += 4) {
        uint2 E[4]; uint4 q[4];
#pragma unroll
        for (int j = 0; j < 4; j++) E[j] = p.sedge[e + j];
#pragma unroll
        for (int j = 0; j < 4; j++) q[j] = tab[(size_t)E[j].x * 16 + lane];
#pragma unroll
        for (int j = 0; j < 4; j++) {
            float w = __uint_as_float(E[j].y);
            aL.x += w * blo(q[j].x); aL.y += w * bhi(q[j].x);
            aL.z += w * blo(q[j].y); aL.w += w * bhi(q[j].y);
            aH.x += w * blo(q[j].z); aH.y += w * bhi(q[j].z);
            aH.z += w * blo(q[j].w); aH.w += w * bhi(q[j].w);
        }
    }
    for (; e < end; ++e) {
        uint2 E = p.sedge[e];
        float w = __uint_as_float(E.y);
        uint4 q = tab[(size_t)E.x * 16 + lane];
        aL.x += w * blo(q.x); aL.y += w * bhi(q.x);
        aL.z += w * blo(q.y); aL.w += w * bhi(q.y);
        aH.x += w * blo(q.z); aH.y += w * bhi(q.z);
        aH.z += w * blo(q.w); aH.w += w * bhi(q.w);
    }

    float d = p.dinv[node];
    float4 b0 = ((const float4*)bias)[lane * 2];
    float4 b1 = ((const float4*)bias)[lane * 2 + 1];
    aL.x = fmaxf(fmaf(d, aL.x, b0.x), 0.f);
    aL.y = fmaxf(fmaf(d, aL.y, b0.y), 0.f);
    aL.z = fmaxf(fmaf(d, aL.z, b0.z), 0.f);
    aL.w = fmaxf(fmaf(d, aL.w, b0.w), 0.f);
    aH.x = fmaxf(fmaf(d, aH.x, b1.x), 0.f);
    aH.y = fmaxf(fmaf(d, aH.y, b1.y), 0.f);
    aH.z = fmaxf(fmaf(d, aH.z, b1.z), 0.f);
    aH.w = fmaxf(fmaf(d, aH.w, b1.w), 0.f);

    if (last) {
        float4 w0 = ((const float4*)p.lw)[lane * 2];
        float4 w1 = ((const float4*)p.lw)[lane * 2 + 1];
        float pr = aL.x * w0.x + aL.y * w0.y + aL.z * w0.z + aL.w * w0.w +
                   aH.x * w1.x + aH.y * w1.y + aH.z * w1.z + aH.w * w1.w;
#pragma unroll
        for (int off = 8; off; off >>= 1) pr += __shfl_down(pr, off);
        if (lane == 0) p.out[node] = pr + p.lb[0];
    } else {
        uint4 o;
        o.x = (unsigned int)bf16rne(aL.x) | ((unsigned int)bf16rne(aL.y) << 16);
        o.y = (unsigned int)bf16rne(aL.z) | ((unsigned int)bf16rne(aL.w) << 16);
        o.z = (unsigned int)bf16rne(aH.x) | ((unsigned int)bf16rne(aH.y) << 16);
        o.w = (unsigned int)bf16rne(aH.z) | ((unsigned int)bf16rne(aH.w) << 16);
        ((uint4*)p.hb)[(size_t)node * 16 + lane] = o;
    }
}

// ---------------- the mega kernel ------------------------------------------
__global__ __launch_bounds__(256, 6) void mega(Prm p) {
    cg::grid_group gg = cg::this_grid();
    __shared__ SMem sm;
    const int t   = threadIdx.x;
    const int bid = blockIdx.x;
    const int gsz = gridDim.x;

    // P0: Wt transpose/cast (3 layers) + zero gbcur
    for (int i = bid * 256 + t; i < 3 * 16384; i += gsz * 256) {
        int layer = i >> 14, j = i & 16383;
        const float* W = layer == 0 ? p.W1 : (layer == 1 ? p.W2 : p.W3);
        int n = j >> 7, k = j & 127;
        p.Wt[i] = bf16rne(W[k * 128 + n]);
    }
    if (bid == 0 && t < 128) p.gbcur[t] = 0;
    gg.sync();

    // P1: binA
    for (int vb = bid; vb < NVB_A; vb += gsz) binA_vb(p, sm, vb);
    gg.sync();

    // P2: binB
    for (int vb = bid; vb < NB; vb += gsz) binB_vb(p, sm, vb);
    gg.sync();

    // layers
    for (int layer = 0; layer < 3; layer++) {
        for (int vb = bid; vb < NVB_G; vb += gsz) gemm_vb(p, sm, vb, layer);
        gg.sync();
        const float* bias = layer == 0 ? p.b1 : (layer == 1 ? p.b2 : p.b3);
        for (int vb = bid; vb < NVB_S; vb += gsz) gather_vb(p, vb, bias, layer == 2);
        if (layer < 2) gg.sync();
    }
}

extern "C" void kernel_launch(void* const* d_in, const int* in_sizes, int n_in,
                              void* d_out, int out_size, void* d_ws, size_t ws_size,
                              hipStream_t stream) {
    Prm p;
    p.x   = (const float*)d_in[0];
    const int* ei = (const int*)d_in[1];   // int64 in reference -> int32 on device
    p.row = ei;
    p.col = ei + NE;
    p.ea  = (const float*)d_in[2];
    p.W1  = (const float*)d_in[3];
    p.b1  = (const float*)d_in[4];
    p.W2  = (const float*)d_in[5];
    p.b2  = (const float*)d_in[6];
    p.W3  = (const float*)d_in[7];
    p.b3  = (const float*)d_in[8];
    p.lw  = (const float*)d_in[9];
    p.lb  = (const float*)d_in[10];
    p.out = (float*)d_out;

    char* wsb = (char*)d_ws;
    p.babuf   = (uint2*)wsb;          wsb += (size_t)NB * BCAP * 8;
    p.sedge   = (uint2*)wsb;          wsb += (size_t)NB * BCAP * 8;
    p.cursor2 = (uint2*)wsb;          wsb += (size_t)N_NODES * 8;
    p.dinv    = (float*)wsb;          wsb += (size_t)N_NODES * 4;
    p.gbcur   = (int*)wsb;            wsb += 128 * 4;
    p.Wt      = (unsigned short*)wsb; wsb += 3 * 16384 * 2;
    p.xwb     = (unsigned short*)wsb; wsb += (size_t)N_NODES * C * 2;
    p.hb      = (unsigned short*)wsb;

    int maxB = 0;
    hipOccupancyMaxActiveBlocksPerMultiprocessor(&maxB, mega, 256, 0);
    if (maxB < 1) maxB = 1;
    int grid = 256 * maxB;   // 256 CUs on MI355X

    void* args[] = { (void*)&p };
    hipLaunchCooperativeKernel((const void*)mega, dim3(grid), dim3(256), args, 0, stream);
}